// Round 1
// baseline (84.194 us; speedup 1.0000x reference)
//
#include <hip/hip_runtime.h>
#include <math.h>

// Black-oil Peaceman well loss.
// X: (4096, 89, 128) f32;  Y: (4096, 66, 128) f32;  out: (4096, 66, 128) f32.
// out[n, k,      s] = (|dd|*B/(UO*bo)  * perm*kro - Y[n,k,s])      * 1e-10/N
// out[n, 22+k,   s] = (|dd|*B          * perm*krw - Y[n,22+k,s])   * 1e-10/N
// out[n, 44+k,   s] = (|dd|*B/(mug*bg) * perm*krg - Y[n,44+k,s])   * 1e-10/N
// where B = 2*pi*DZ/ln(RE/RWELL), dd = mean_s(X[n,22,s]) - 100.

#define N_BATCH   4096
#define XC        89
#define YC        66
#define S         128
#define PI_F      3.14159265358979323846f
#define LN2_F     0.6931471805599453f

// ---------------- kernel 1: per-n scalars ----------------
__global__ void __launch_bounds__(64) pmean_kernel(const float* __restrict__ X,
                                                   float* __restrict__ coef) {
    const int n    = blockIdx.x;
    const int lane = threadIdx.x;              // 64 lanes
    const float* row = X + (size_t)n * (XC * S) + 22 * S;
    float2 v = *reinterpret_cast<const float2*>(row + lane * 2);
    float sum = v.x + v.y;
    #pragma unroll
    for (int off = 32; off > 0; off >>= 1)
        sum += __shfl_down(sum, off, 64);
    if (lane == 0) {
        const float p  = sum * (1.0f / (float)S);
        const float dd = p - 100.0f;                 // drawdown (negative)
        const bool  lt = (p < 0.5f);                 // p < P_BUB
        // bg = exp(-0.0017*dp)
        const float dp = lt ? (0.1f - p) : (0.1f - 0.5f);
        const float bg = expf(-0.0017f * dp);
        // bo = exp(-(e1+e2))
        const float e1 = lt ? (-8e-5f * (0.1f - p)) : (-8e-5f * (0.1f - 0.5f));
        const float e2 = -1e-5f * (lt ? 0.0f : (p - 0.5f));
        const float bo = expf(-(e1 + e2));
        const float mug = 3e-10f * p * p + 1e-6f * p + 0.0133f;
        const float base = 2.0f * PI_F * 100.0f / LN2_F;   // 2*pi*DZ / ln(RE/RWELL)
        const float add  = fabsf(dd) * base;
        float4 c;
        c.x = add / (2.5f * bo);        // oil:   UO * bo
        c.y = add;                      // water: UW * BW = 1
        c.z = add / (mug * bg);         // gas
        c.w = 0.0f;
        *reinterpret_cast<float4*>(coef + n * 4) = c;
    }
}

// ---------------- kernel 2: streaming elementwise ----------------
#define COMP(v, j) ((&(v).x)[j])

__global__ void __launch_bounds__(256) blackoil_kernel(const float* __restrict__ X,
                                                       const float* __restrict__ Y,
                                                       const float* __restrict__ coef,
                                                       float* __restrict__ out) {
    const int tid = blockIdx.x * 256 + threadIdx.x;
    const int s4  = tid & 31;          // which group of 4 s-values
    const int row = tid >> 5;          // n*22 + k
    const int k   = row % 22;
    const int n   = row / 22;

    const float* xb = X   + (size_t)n * (XC * S);
    const float* yb = Y   + (size_t)n * (YC * S);
    float*       ob = out + (size_t)n * (YC * S);
    const int so = s4 * 4;

    const float4 perm = *reinterpret_cast<const float4*>(xb + k * S + so);
    const float4 sg   = *reinterpret_cast<const float4*>(xb + (45 + k) * S + so);
    const float4 sw   = *reinterpret_cast<const float4*>(xb + (67 + k) * S + so);
    const float4 r_o  = *reinterpret_cast<const float4*>(yb + k * S + so);
    const float4 r_w  = *reinterpret_cast<const float4*>(yb + (22 + k) * S + so);
    const float4 r_g  = *reinterpret_cast<const float4*>(yb + (44 + k) * S + so);
    const float4 c    = *reinterpret_cast<const float4*>(coef + n * 4);

    const float inv_denom = 1.0f / 0.7f;            // 1/(1-SWI-SOR)
    const float scale     = 1e-10f / (float)N_BATCH;

    float4 o_o, o_w, o_g;
    #pragma unroll
    for (int j = 0; j < 4; ++j) {
        const float swn = (COMP(sw, j) - 0.1f) * inv_denom;
        const float sgn = COMP(sg, j) * inv_denom;
        const float krw = 0.3f * swn * swn;
        const float aa  = 1.0f - swn;
        const float bb  = 1.0f - sgn;
        const float kro = 0.9f * (aa * aa) * (bb * bb);
        const float krg = 0.8f * sgn * sgn;
        const float pk  = COMP(perm, j);
        COMP(o_o, j) = (fabsf(c.x * pk * kro) - COMP(r_o, j)) * scale;
        COMP(o_w, j) = (fabsf(c.y * pk * krw) - COMP(r_w, j)) * scale;
        COMP(o_g, j) = (fabsf(c.z * pk * krg) - COMP(r_g, j)) * scale;
    }

    *reinterpret_cast<float4*>(ob + k * S + so)        = o_o;
    *reinterpret_cast<float4*>(ob + (22 + k) * S + so) = o_w;
    *reinterpret_cast<float4*>(ob + (44 + k) * S + so) = o_g;
}

extern "C" void kernel_launch(void* const* d_in, const int* in_sizes, int n_in,
                              void* d_out, int out_size, void* d_ws, size_t ws_size,
                              hipStream_t stream) {
    const float* X = (const float*)d_in[0];
    const float* Y = (const float*)d_in[1];
    float* out  = (float*)d_out;
    float* coef = (float*)d_ws;                 // 4096 * 4 floats = 64 KB

    pmean_kernel<<<N_BATCH, 64, 0, stream>>>(X, coef);

    const int total  = N_BATCH * 22 * (S / 4);  // threads
    const int blocks = total / 256;             // exact: 11264
    blackoil_kernel<<<blocks, 256, 0, stream>>>(X, Y, coef, out);
}